// Round 6
// baseline (35.175 us; speedup 1.0000x reference)
//
#include <hip/hip_runtime.h>

// TrajLoss: pos = cumsum(pred.reshape(B,T,2), axis=1);
// loss = sum((pos_x - true[:, :T])^2 + (pos_y - true[:, T:])^2)
// B=8192, L=2048, T=1024. traj_du_true (d_in[1]) is unused by the reference.
//
// R5 post-mortem: load pattern AND HBM traffic are irrelevant (coalesced ==
// strided; L3-resident replays same time). VGPR=44 proves the compiler
// serializes load->wait->consume (24 in-flight loads need ~80 VGPRs), so
// each wave eats ~3-4 L3 round-trips serially and 12 waves/CU can't hide it.
// Fix: TLP, not MLP. One block per ROW, 4 waves cooperate (8192 blocks,
// 4x the waves, 6 load-instrs/wave, cross-wave carry via 4-float LDS).
// Default launch bounds -> 8 blocks/CU = 32 waves/CU.

constexpr int L_DIM = 2048;
constexpr int T_DIM = 1024;   // L/2

__global__ __launch_bounds__(256) void traj_loss_kernel(
    const float* __restrict__ pred,
    const float* __restrict__ pos_true,
    float* __restrict__ partials,
    int B)
{
    const int w    = threadIdx.x >> 6;    // wave 0..3: owns t-range [w*256,(w+1)*256)
    const int lane = threadIdx.x & 63;
    const int row  = blockIdx.x;

    const float4* p4  = reinterpret_cast<const float4*>(pred + (size_t)row * L_DIM);          // 512 float4
    const float2* tX2 = reinterpret_cast<const float2*>(pos_true + (size_t)row * L_DIM);      // 512 float2
    const float2* tY2 = reinterpret_cast<const float2*>(pos_true + (size_t)row * L_DIM + T_DIM);

    // ---- coalesced loads: wave w, chunk j, index k = w*128 + j*64 + lane ----
    // float4 k of pred  = (dx,dy) for t=2k, 2k+1
    // float2 k of tx/ty = truth   for t=2k, 2k+1
    const int k0 = w * 128 + lane;
    float4 v0 = p4[k0],        v1 = p4[k0 + 64];
    float2 tx0 = tX2[k0],      tx1 = tX2[k0 + 64];
    float2 ty0 = tY2[k0],      ty1 = tY2[k0 + 64];

    // ---- per-lane pair sums, 2 chunks x 2 axes ----
    const float ox0 = v0.x + v0.z, oy0 = v0.y + v0.w;
    const float ox1 = v1.x + v1.z, oy1 = v1.y + v1.w;

    // ---- wave inclusive scans (2 chunks x 2 axes, interleaved) ----
    float ix0 = ox0, ix1 = ox1, iy0 = oy0, iy1 = oy1;
#pragma unroll
    for (int d = 1; d < 64; d <<= 1) {
        float a = __shfl_up(ix0, d);
        float b = __shfl_up(ix1, d);
        float c = __shfl_up(iy0, d);
        float e = __shfl_up(iy1, d);
        if (lane >= d) { ix0 += a; ix1 += b; iy0 += c; iy1 += e; }
    }
    const float t0x = __shfl(ix0, 63), t0y = __shfl(iy0, 63);   // chunk-0 wave total
    const float t1x = __shfl(ix1, 63), t1y = __shfl(iy1, 63);   // chunk-1 wave total

    // ---- cross-wave carry via LDS ----
    __shared__ float wsum_x[4], wsum_y[4];
    __shared__ float warp_acc[4];
    if (lane == 0) { wsum_x[w] = t0x + t1x; wsum_y[w] = t0y + t1y; }
    __syncthreads();
    float cx = 0.0f, cy = 0.0f;
#pragma unroll
    for (int ww = 0; ww < 3; ++ww)
        if (ww < w) { cx += wsum_x[ww]; cy += wsum_y[ww]; }

    // ---- squared error ----
    float acc = 0.0f;
    {
        // chunk 0: exclusive prefix = carry + (ix0 - ox0)
        float rx = cx + (ix0 - ox0), ry = cy + (iy0 - oy0), e;
        rx += v0.x; e = rx - tx0.x; acc += e * e;
        ry += v0.y; e = ry - ty0.x; acc += e * e;
        rx += v0.z; e = rx - tx0.y; acc += e * e;
        ry += v0.w; e = ry - ty0.y; acc += e * e;
    }
    {
        // chunk 1: carry + chunk-0 wave total + (ix1 - ox1)
        float rx = cx + t0x + (ix1 - ox1), ry = cy + t0y + (iy1 - oy1), e;
        rx += v1.x; e = rx - tx1.x; acc += e * e;
        ry += v1.y; e = ry - ty1.x; acc += e * e;
        rx += v1.z; e = rx - tx1.y; acc += e * e;
        ry += v1.w; e = ry - ty1.y; acc += e * e;
    }

    // ---- wave reduce, then block reduce ----
#pragma unroll
    for (int d = 32; d >= 1; d >>= 1) acc += __shfl_xor(acc, d);

    if (lane == 0) warp_acc[w] = acc;
    __syncthreads();
    if (threadIdx.x == 0)
        partials[row] = warp_acc[0] + warp_acc[1] + warp_acc[2] + warp_acc[3];
}

__global__ __launch_bounds__(256) void reduce_kernel(
    const float* __restrict__ partials, float* __restrict__ out, int n)
{
    const int lane = threadIdx.x & 63;
    const int wid  = threadIdx.x >> 6;

    float s = 0.0f;
    for (int i = threadIdx.x; i < n; i += 256) s += partials[i];

#pragma unroll
    for (int d = 32; d >= 1; d >>= 1) s += __shfl_xor(s, d);

    __shared__ float ws[4];
    if (lane == 0) ws[wid] = s;
    __syncthreads();

    if (threadIdx.x == 0) out[0] = ws[0] + ws[1] + ws[2] + ws[3];
}

extern "C" void kernel_launch(void* const* d_in, const int* in_sizes, int n_in,
                              void* d_out, int out_size, void* d_ws, size_t ws_size,
                              hipStream_t stream) {
    const float* pred     = (const float*)d_in[0];  // traj_pred
    // d_in[1] = traj_du_true — unused by the reference
    const float* pos_true = (const float*)d_in[2];  // traj_pos_true
    float* out      = (float*)d_out;
    float* partials = (float*)d_ws;                 // B floats, overwritten every call

    const int B = in_sizes[0] / L_DIM;              // 8192

    traj_loss_kernel<<<B, 256, 0, stream>>>(pred, pos_true, partials, B);
    reduce_kernel<<<1, 256, 0, stream>>>(partials, out, B);
}

// Round 7
// 30.157 us; speedup vs baseline: 1.1664x; 1.1664x over previous
//
#include <hip/hip_runtime.h>

// TrajLoss: pos = cumsum(pred.reshape(B,T,2), axis=1);
// loss = sum((pos_x - true[:, :T])^2 + (pos_y - true[:, T:])^2)
// B=8192, L=2048, T=1024. traj_du_true (d_in[1]) is unused by the reference.
//
// R1-R6 synthesis: K1 is pinned at ~21 us regardless of load pattern, HBM
// traffic (L3-resident replays identical), or occupancy -> the L3->CU
// delivery wall (~6.4 TB/s, HBM-class). Remaining cost was structure:
// 1-block K2 + second launch (~5-6 us) and (R1) same-address atomic
// serialization (2048 atomics = 45 us floor). This version: ONE kernel,
// 512 blocks x 512 threads (8 waves), 2 rows per wave, block LDS reduce,
// ONE atomicAdd per block (512 total -- absorbed during compute, no tail).

constexpr int L_DIM = 2048;
constexpr int T_DIM = 1024;          // L/2
constexpr int WAVES_PER_BLOCK = 8;   // 512 threads
constexpr int GRID = 512;

__global__ __launch_bounds__(512) void traj_loss_kernel(
    const float* __restrict__ pred,
    const float* __restrict__ pos_true,
    float* __restrict__ out,
    int B)
{
    const int wid  = threadIdx.x >> 6;
    const int lane = threadIdx.x & 63;
    const int gwave  = blockIdx.x * WAVES_PER_BLOCK + wid;
    const int nwaves = gridDim.x * WAVES_PER_BLOCK;

    float acc = 0.0f;

    for (int row = gwave; row < B; row += nwaves) {
        const float4* p4 = reinterpret_cast<const float4*>(pred + (size_t)row * L_DIM);          // 512 float4
        const float4* tX = reinterpret_cast<const float4*>(pos_true + (size_t)row * L_DIM);      // 256 float4
        const float4* tY = reinterpret_cast<const float4*>(pos_true + (size_t)row * L_DIM + T_DIM);

        // ---- loads: lane owns 64 B contiguous per segment, 2 segments ----
        float4 v[2][4];     // pred: segment s, lane base s*256 + lane*4
        float4 tx[2][2];    // truth x: s*128 + lane*2
        float4 ty[2][2];
#pragma unroll
        for (int s = 0; s < 2; ++s)
#pragma unroll
            for (int q = 0; q < 4; ++q)
                v[s][q] = p4[s * 256 + lane * 4 + q];
#pragma unroll
        for (int s = 0; s < 2; ++s)
#pragma unroll
            for (int r = 0; r < 2; ++r)
                tx[s][r] = tX[s * 128 + lane * 2 + r];
#pragma unroll
        for (int s = 0; s < 2; ++s)
#pragma unroll
            for (int r = 0; r < 2; ++r)
                ty[s][r] = tY[s * 128 + lane * 2 + r];

        // ---- per-lane segment totals ----
        float sx[2], sy[2];
#pragma unroll
        for (int s = 0; s < 2; ++s) {
            sx[s] = (v[s][0].x + v[s][0].z) + (v[s][1].x + v[s][1].z)
                  + (v[s][2].x + v[s][2].z) + (v[s][3].x + v[s][3].z);
            sy[s] = (v[s][0].y + v[s][0].w) + (v[s][1].y + v[s][1].w)
                  + (v[s][2].y + v[s][2].w) + (v[s][3].y + v[s][3].w);
        }

        // ---- 2 segments x 2 axes wave inclusive scans (interleaved) ----
        float ix0 = sx[0], ix1 = sx[1], iy0 = sy[0], iy1 = sy[1];
#pragma unroll
        for (int d = 1; d < 64; d <<= 1) {
            float a = __shfl_up(ix0, d);
            float b = __shfl_up(ix1, d);
            float c = __shfl_up(iy0, d);
            float e = __shfl_up(iy1, d);
            if (lane >= d) { ix0 += a; ix1 += b; iy0 += c; iy1 += e; }
        }
        const float totx0 = __shfl(ix0, 63);   // segment-0 row total
        const float toty0 = __shfl(iy0, 63);

        // ---- error accumulation (all indices compile-time static) ----
#define SEG(s, bx, by)                                                  \
        { float rx = (bx), ry = (by), e;                                \
          rx += v[s][0].x; e = rx - tx[s][0].x; acc += e * e;           \
          ry += v[s][0].y; e = ry - ty[s][0].x; acc += e * e;           \
          rx += v[s][0].z; e = rx - tx[s][0].y; acc += e * e;           \
          ry += v[s][0].w; e = ry - ty[s][0].y; acc += e * e;           \
          rx += v[s][1].x; e = rx - tx[s][0].z; acc += e * e;           \
          ry += v[s][1].y; e = ry - ty[s][0].z; acc += e * e;           \
          rx += v[s][1].z; e = rx - tx[s][0].w; acc += e * e;           \
          ry += v[s][1].w; e = ry - ty[s][0].w; acc += e * e;           \
          rx += v[s][2].x; e = rx - tx[s][1].x; acc += e * e;           \
          ry += v[s][2].y; e = ry - ty[s][1].x; acc += e * e;           \
          rx += v[s][2].z; e = rx - tx[s][1].y; acc += e * e;           \
          ry += v[s][2].w; e = ry - ty[s][1].y; acc += e * e;           \
          rx += v[s][3].x; e = rx - tx[s][1].z; acc += e * e;           \
          ry += v[s][3].y; e = ry - ty[s][1].z; acc += e * e;           \
          rx += v[s][3].z; e = rx - tx[s][1].w; acc += e * e;           \
          ry += v[s][3].w; e = ry - ty[s][1].w; acc += e * e; }

        SEG(0, ix0 - sx[0],         iy0 - sy[0]);
        SEG(1, totx0 + ix1 - sx[1], toty0 + iy1 - sy[1]);
#undef SEG
    }

    // ---- wave reduce ----
#pragma unroll
    for (int d = 32; d >= 1; d >>= 1) acc += __shfl_xor(acc, d);

    __shared__ float warp_sums[WAVES_PER_BLOCK];
    if (lane == 0) warp_sums[wid] = acc;
    __syncthreads();

    if (threadIdx.x == 0) {
        float s = 0.0f;
#pragma unroll
        for (int w = 0; w < WAVES_PER_BLOCK; ++w) s += warp_sums[w];
        atomicAdd(out, s);   // 512 total, absorbed during compute
    }
}

extern "C" void kernel_launch(void* const* d_in, const int* in_sizes, int n_in,
                              void* d_out, int out_size, void* d_ws, size_t ws_size,
                              hipStream_t stream) {
    const float* pred     = (const float*)d_in[0];  // traj_pred
    // d_in[1] = traj_du_true — unused by the reference
    const float* pos_true = (const float*)d_in[2];  // traj_pos_true
    float* out = (float*)d_out;

    const int B = in_sizes[0] / L_DIM;              // 8192

    // d_out is poisoned (0xAA) by the harness — zero it every call
    // (memset node is graph-capturable).
    hipMemsetAsync(out, 0, sizeof(float), stream);

    traj_loss_kernel<<<GRID, 512, 0, stream>>>(pred, pos_true, out, B);
}